// Round 3
// baseline (1195.814 us; speedup 1.0000x reference)
//
#include <hip/hip_runtime.h>
#include <stdint.h>

// Problem constants: B=16, Lt=128, Lv=4096, D=1024, H=16, HD=64
typedef short  s16x8 __attribute__((ext_vector_type(8)));   // 8 bf16 (4 VGPR) MFMA frag
typedef float  f32x4 __attribute__((ext_vector_type(4)));   // MFMA acc
typedef unsigned short u16x4 __attribute__((ext_vector_type(4)));

__device__ __forceinline__ unsigned short f2bf(float f) {   // RNE f32->bf16
  unsigned u = __builtin_bit_cast(unsigned, f);
  u = (u + 0x7fffu + ((u >> 16) & 1u)) >> 16;
  return (unsigned short)u;
}

__device__ __forceinline__ void glds16(const void* g, void* l) {
  // async global->LDS, 16B/lane; LDS dst = wave-uniform base + lane*16
  __builtin_amdgcn_global_load_lds((const __attribute__((address_space(1))) void*)g,
                                   (__attribute__((address_space(3))) void*)l, 16, 0, 0);
}

__device__ __forceinline__ f32x4 mfma16(s16x8 a, s16x8 b, f32x4 c) {
  return __builtin_amdgcn_mfma_f32_16x16x32_bf16(a, b, c, 0, 0, 0);
}

#define VM4 asm volatile("s_waitcnt vmcnt(4)" ::: "memory")
#define VM0 asm volatile("s_waitcnt vmcnt(0)" ::: "memory")

// ---------------- hidden fp32 -> bf16 one-pass convert (memory-bound) ----------
__global__ __launch_bounds__(256) void kt_cvt(const float* __restrict__ X,
                                              unsigned short* __restrict__ Y) {
  const size_t N8 = (size_t)16 * 4096 * 1024 / 8;
  for (size_t i = (size_t)blockIdx.x * 256 + threadIdx.x; i < N8;
       i += (size_t)gridDim.x * 256) {
    const float* g = X + i * 8;
    f32x4 a = *(const f32x4*)g;
    f32x4 b = *(const f32x4*)(g + 4);
    s16x8 o;
    o[0]=f2bf(a[0]); o[1]=f2bf(a[1]); o[2]=f2bf(a[2]); o[3]=f2bf(a[3]);
    o[4]=f2bf(b[0]); o[5]=f2bf(b[1]); o[6]=f2bf(b[2]); o[7]=f2bf(b[3]);
    *(s16x8*)(Y + i * 8) = o;
  }
}

// ---------------- weight transpose: W[k][n] f32 -> WT[n][k] bf16 -----------------
__global__ void kt_transpose(const float* __restrict__ W, unsigned short* __restrict__ WT) {
  __shared__ float tile[64][65];
  int n0 = blockIdx.x * 64, k0 = blockIdx.y * 64;
  int tx = threadIdx.x, ty = threadIdx.y;  // 64 x 4
  #pragma unroll
  for (int r = ty; r < 64; r += 4)
    tile[r][tx] = W[(size_t)(k0 + r) * 1024 + n0 + tx];
  __syncthreads();
  #pragma unroll
  for (int r = ty; r < 64; r += 4)
    WT[(size_t)(n0 + r) * 1024 + k0 + tx] = f2bf(tile[tx][r]);
}

// ---------------- small GEMM (Q projection): C = A(M,1024)@BT^T + bias ----------
// A fp32 (text), out bf16 Qb with torch-.view scramble + *0.125
__global__ __launch_bounds__(256, 2) void kt_gemm_q(
    const float* __restrict__ Ain, const unsigned short* __restrict__ BT,
    const float* __restrict__ bias, unsigned short* __restrict__ Cout) {
  __shared__ __align__(16) unsigned short As[128 * 32];
  __shared__ __align__(16) unsigned short Bs[128 * 32];
  const int tid = threadIdx.x, lane = tid & 63, wave = tid >> 6;
  const int l15 = lane & 15, quad = lane >> 4;
  const int wr = wave >> 1, wc = wave & 1;
  const int n0 = blockIdx.x * 128, m0 = blockIdx.y * 128;

  f32x4 acc[4][4] = {};
  for (int k0 = 0; k0 < 1024; k0 += 32) {
    __syncthreads();
    #pragma unroll
    for (int i = 0; i < 2; ++i) {
      int rowb = (wave * 2 + i) * 16 + (lane >> 2);
      glds16(BT + (size_t)(n0 + rowb) * 1024 + k0 + (lane & 3) * 8,
             &Bs[(wave * 2 + i) * 512]);
    }
    {
      const float* A = Ain;
      int row = tid >> 1, ks = (tid & 1) * 16;
      const float* g = &A[(size_t)(m0 + row) * 1024 + k0 + ks];
      f32x4 fa = *(const f32x4*)(g);
      f32x4 fb = *(const f32x4*)(g + 4);
      f32x4 fc = *(const f32x4*)(g + 8);
      f32x4 fd = *(const f32x4*)(g + 12);
      s16x8 lo, hi;
      lo[0]=f2bf(fa[0]); lo[1]=f2bf(fa[1]); lo[2]=f2bf(fa[2]); lo[3]=f2bf(fa[3]);
      lo[4]=f2bf(fb[0]); lo[5]=f2bf(fb[1]); lo[6]=f2bf(fb[2]); lo[7]=f2bf(fb[3]);
      hi[0]=f2bf(fc[0]); hi[1]=f2bf(fc[1]); hi[2]=f2bf(fc[2]); hi[3]=f2bf(fc[3]);
      hi[4]=f2bf(fd[0]); hi[5]=f2bf(fd[1]); hi[6]=f2bf(fd[2]); hi[7]=f2bf(fd[3]);
      *(s16x8*)&As[row * 32 + ks] = lo;
      *(s16x8*)&As[row * 32 + ks + 8] = hi;
    }
    __syncthreads();
    s16x8 a[4], b[4];
    #pragma unroll
    for (int i = 0; i < 4; ++i) a[i] = *(const s16x8*)&As[(wr * 64 + i * 16 + l15) * 32 + quad * 8];
    #pragma unroll
    for (int j = 0; j < 4; ++j) b[j] = *(const s16x8*)&Bs[(wc * 64 + j * 16 + l15) * 32 + quad * 8];
    #pragma unroll
    for (int i = 0; i < 4; ++i)
      #pragma unroll
      for (int j = 0; j < 4; ++j) acc[i][j] = mfma16(a[i], b[j], acc[i][j]);
  }
  #pragma unroll
  for (int j = 0; j < 4; ++j) {
    int col = n0 + wc * 64 + j * 16 + l15;
    float bv = bias[col];
    #pragma unroll
    for (int i = 0; i < 4; ++i)
      #pragma unroll
      for (int r = 0; r < 4; ++r) {
        int row = m0 + wr * 64 + i * 16 + quad * 4 + r;
        float v = (acc[i][j][r] + bv) * 0.125f;
        size_t idx = ((size_t)((row >> 7) * 16 + (col >> 6)) * 128 + (row & 127)) * 64 + (col & 63);
        Cout[idx] = f2bf(v);
      }
  }
}

// ---------------- 256x256 8-phase bf16 GEMM (T1+T2+T3+T4+T5) --------------------
// A: bf16 [65536][1024] row-major.
// MODE 0: fused K+V projection. BT = [WkT(1024 rows); WvT(1024 rows)] (contiguous),
//         N=2048, grid 2048. cols<1024 -> Ko[b][h][s][hd]; cols>=1024 -> Vt[b][h][hd][s].
// MODE 2: O-projection. BT = WoT, N=1024, grid 1024, fp32 row-major out + bias.
// T1: chunked XCD swizzle (bid%8 -> contiguous logical chunk), n-fast decomposition
//     => each XCD's 32 co-resident blocks = {4 m-panels x all NN n-blocks}: A-panel
//     fetched once per XCD window (L2 reuse), per-XCD HBM A-stream cut NNx.
// Schedule: even tile in buf0 (P0-P3), odd in buf1 (P4-P7); stages P0:A(odd),
// P1/P2:B(even+2), P4/P5:A(even+2), P5/P6:B(odd+2); vmcnt(4) at end-P3/P7 before
// the phase-end barrier (cross-wave landing guarantee). LDS 16B-chunk XOR swizzle
// (pre-swizzled glds SOURCE + swizzled ds_read, linear dest) => 0 bank conflicts.
template <int MODE>
__global__ __launch_bounds__(512, 2) void kt_gemm256(
    const unsigned short* __restrict__ A, const unsigned short* __restrict__ BT,
    const float* __restrict__ bias0, const float* __restrict__ bias1,
    void* __restrict__ out0, void* __restrict__ out1) {
  constexpr int NN = (MODE == 0) ? 8 : 4;          // n-blocks
  constexpr int CHUNK = (MODE == 0) ? 256 : 128;   // nwg/8 (nwg divisible by 8)
  __shared__ __align__(16) unsigned short lds[65536];  // 128 KiB
  const int tid = threadIdx.x, lane = tid & 63, wave = tid >> 6;
  const int l15 = lane & 15, quad = lane >> 4;
  const int wr = wave >> 2, wc = wave & 3;        // 2M x 4N waves
  const int r0 = lane >> 3, sck = (lane & 7) ^ r0; // stage source pre-swizzle
  const int bid = blockIdx.x;
  const int logical = (bid & 7) * CHUNK + (bid >> 3);   // bijective chunked swizzle
  const int nblk = logical & (NN - 1), mblk = logical / NN;
  const int n0 = nblk * 256, m0 = mblk * 256;
  const unsigned short* Asrc = A + (size_t)m0 * 1024;
  const unsigned short* Bsrc = BT + (size_t)n0 * 1024;

  f32x4 acc[8][4] = {};
  s16x8 bf_[4][2];

  auto stageA = [&](int t, int h, int buf) {
    #pragma unroll
    for (int is = 0; is < 2; ++is) {
      int c = wave * 2 + is;
      glds16(Asrc + (size_t)(h * 128 + c * 8 + r0) * 1024 + t * 64 + sck * 8,
             &lds[buf * 32768 + h * 8192 + c * 512]);
    }
  };
  auto stageB = [&](int t, int h, int buf) {
    #pragma unroll
    for (int is = 0; is < 2; ++is) {
      int c = wave * 2 + is;
      glds16(Bsrc + (size_t)(h * 128 + c * 8 + r0) * 1024 + t * 64 + sck * 8,
             &lds[buf * 32768 + 16384 + h * 8192 + c * 512]);
    }
  };

  // prologue: tile0 full (buf0) then tile1's B halves (buf1); order matters for vmcnt
  stageA(0, 0, 0); stageA(0, 1, 0); stageB(0, 0, 0); stageB(0, 1, 0);
  stageB(1, 0, 1); stageB(1, 1, 1);
  VM4;                               // tile0 landed (B(1) may be in flight)
  __builtin_amdgcn_s_barrier();

  #pragma unroll 1
  for (int it = 0; it < 8; ++it) {
    const bool last = (it == 7);
    const int te = 2 * it;
    #pragma unroll
    for (int half = 0; half < 2; ++half) {     // half0: tile te (buf0); half1: te+1 (buf1)
      const int buf = half;
      #pragma unroll
      for (int p = 0; p < 4; ++p) {
        if (p == 0) {  // B-frags for this tile (held across 4 phases)
          #pragma unroll
          for (int j = 0; j < 4; ++j)
            #pragma unroll
            for (int kk = 0; kk < 2; ++kk) {
              int r = (wc & 1) * 64 + j * 16 + l15;
              bf_[j][kk] = *(const s16x8*)&lds[buf * 32768 + 16384 + (wc >> 1) * 8192
                                               + r * 64 + (((kk * 4 + quad) ^ (r & 7)) << 3)];
            }
        }
        s16x8 af[2][2];
        #pragma unroll
        for (int ii = 0; ii < 2; ++ii)
          #pragma unroll
          for (int kk = 0; kk < 2; ++kk) {
            int r = (p * 2 + ii) * 16 + l15;
            af[ii][kk] = *(const s16x8*)&lds[buf * 32768 + wr * 8192
                                             + r * 64 + (((kk * 4 + quad) ^ (r & 7)) << 3)];
          }
        // --- prefetch stages (hazard-safe slots; see header comment)
        if (half == 0) {
          if (p == 0) { stageA(te + 1, 0, 1); stageA(te + 1, 1, 1); }
          else if (p == 1) { if (!last) stageB(te + 2, 0, 0); }
          else if (p == 2) { if (!last) stageB(te + 2, 1, 0); }
        } else {
          if (p == 0) { if (!last) stageA(te + 2, 0, 0); }
          else if (p == 1) { if (!last) { stageA(te + 2, 1, 0); stageB(te + 3, 0, 1); } }
          else if (p == 2) { if (!last) stageB(te + 3, 1, 1); }
        }
        __builtin_amdgcn_s_barrier();
        __builtin_amdgcn_s_setprio(1);
        #pragma unroll
        for (int ii = 0; ii < 2; ++ii)
          #pragma unroll
          for (int j = 0; j < 4; ++j)
            #pragma unroll
            for (int kk = 0; kk < 2; ++kk)
              acc[p * 2 + ii][j] = mfma16(af[ii][kk], bf_[j][kk], acc[p * 2 + ii][j]);
        __builtin_amdgcn_s_setprio(0);
        if (p == 3) {  // counted waits BEFORE phase-end barrier (cross-wave guarantee)
          if (half == 0) { if (last) { VM0; } else { VM4; } }  // tile te+1 landed
          else           { if (!last) { VM4; } }                // tile te+2 landed
        }
        __builtin_amdgcn_s_barrier();
      }
    }
  }

  // ----------------------------- epilogue ---------------------------------------
  const int bb = m0 >> 12;
  const bool isV = (MODE == 0) && (n0 >= 1024);
  const float* bias = isV ? bias1 : bias0;
  #pragma unroll
  for (int j = 0; j < 4; ++j) {
    const int colg = n0 + wc * 64 + j * 16 + l15;
    const int c1 = colg & 1023;
    const float bv = bias[c1];
    const int hcol = c1 >> 6, dcol = c1 & 63;
    #pragma unroll
    for (int i = 0; i < 8; ++i) {
      const int row0 = m0 + wr * 128 + i * 16 + quad * 4;
      const int s = row0 & 4095;
      if constexpr (MODE == 0) {
        if (isV) {
          size_t base = (((size_t)bb * 16 + hcol) * 64 + dcol) * 4096 + s;
          u16x4 w;
          #pragma unroll
          for (int r = 0; r < 4; ++r) w[r] = f2bf(acc[i][j][r] + bv);
          *(u16x4*)&((unsigned short*)out1)[base] = w;
        } else {
          unsigned short* Ko = (unsigned short*)out0;
          size_t base = (((size_t)bb * 16 + hcol) * 4096 + s) * 64 + dcol;
          #pragma unroll
          for (int r = 0; r < 4; ++r) Ko[base + (size_t)r * 64] = f2bf(acc[i][j][r] + bv);
        }
      } else {
        float* O = (float*)out0;
        size_t base = (size_t)row0 * 1024 + colg;
        #pragma unroll
        for (int r = 0; r < 4; ++r) O[base + (size_t)r * 1024] = acc[i][j][r] + bv;
      }
    }
  }
}

// ---------------- attention pass 1: R[t,d]=sum_s exp(S)*v, Z[t]=sum_s exp(S) ----
// 1-D grid 1024 with chunked XCD swizzle: 4 qidx-blocks sharing one bh's K/V panel
// land on the same XCD -> L2 reuse.
__global__ __launch_bounds__(256, 2) void kt_attn1(
    const unsigned short* __restrict__ Qb, const unsigned short* __restrict__ Kb,
    const unsigned short* __restrict__ Vt, float* __restrict__ RpT,
    float* __restrict__ Zp) {
  __shared__ __align__(16) unsigned short Ks[128 * 64];    // [s][d]
  __shared__ __align__(16) unsigned short Vts[64 * 128];   // [d][s]
  __shared__ __align__(16) unsigned short Es[128 * 128];   // [t][s]
  const int tid = threadIdx.x, lane = tid & 63, wave = tid >> 6;
  const int l15 = lane & 15, quad = lane >> 4;
  const int bid = blockIdx.x;
  const int lid = (bid & 7) * 128 + (bid >> 3);   // bijective chunked swizzle
  const int qidx = lid & 3, bh = lid >> 2;
  const size_t kbase = (size_t)bh * 4096 * 64;
  const size_t vbase = (size_t)bh * 64 * 4096;
  s16x8 qa[2][2];
  #pragma unroll
  for (int i = 0; i < 2; ++i)
    #pragma unroll
    for (int kk = 0; kk < 2; ++kk)
      qa[i][kk] = *(const s16x8*)&Qb[((size_t)bh * 128 + wave * 32 + i * 16 + l15) * 64 + kk * 32 + quad * 8];
  s16x8 bones;
  { unsigned short o = (l15 == 0) ? (unsigned short)0x3F80 : (unsigned short)0;
    #pragma unroll
    for (int c2 = 0; c2 < 8; ++c2) bones[c2] = (short)o; }
  f32x4 Racc[2][4] = {};
  f32x4 Zacc[2] = {};
  for (int ch = 0; ch < 8; ++ch) {
    const int s0 = qidx * 1024 + ch * 128;
    __syncthreads();
    #pragma unroll
    for (int i = 0; i < 4; ++i) {
      int srow = (wave * 4 + i) * 8 + (lane >> 3);
      glds16(Kb + kbase + (size_t)(s0 + srow) * 64 + (lane & 7) * 8, &Ks[(wave * 4 + i) * 512]);
    }
    #pragma unroll
    for (int i = 0; i < 4; ++i) {
      int drow = (wave * 4 + i) * 4 + (lane >> 4);
      glds16(Vt + vbase + (size_t)drow * 4096 + s0 + (lane & 15) * 8, &Vts[(wave * 4 + i) * 512]);
    }
    __syncthreads();
    f32x4 Sacc[2][8] = {};
    #pragma unroll
    for (int kk = 0; kk < 2; ++kk) {
      s16x8 bk_[8];
      #pragma unroll
      for (int j = 0; j < 8; ++j)
        bk_[j] = *(const s16x8*)&Ks[(j * 16 + l15) * 64 + kk * 32 + quad * 8];
      #pragma unroll
      for (int i = 0; i < 2; ++i)
        #pragma unroll
        for (int j = 0; j < 8; ++j) Sacc[i][j] = mfma16(qa[i][kk], bk_[j], Sacc[i][j]);
    }
    #pragma unroll
    for (int i = 0; i < 2; ++i)
      #pragma unroll
      for (int j = 0; j < 8; ++j)
        #pragma unroll
        for (int r = 0; r < 4; ++r)
          Es[(wave * 32 + i * 16 + quad * 4 + r) * 128 + j * 16 + l15] = f2bf(__expf(Sacc[i][j][r]));
    #pragma unroll
    for (int kk = 0; kk < 4; ++kk) {
      s16x8 ea[2];
      #pragma unroll
      for (int i2 = 0; i2 < 2; ++i2)
        ea[i2] = *(const s16x8*)&Es[(wave * 32 + i2 * 16 + l15) * 128 + kk * 32 + quad * 8];
      s16x8 bv_[4];
      #pragma unroll
      for (int jd = 0; jd < 4; ++jd)
        bv_[jd] = *(const s16x8*)&Vts[(jd * 16 + l15) * 128 + kk * 32 + quad * 8];
      #pragma unroll
      for (int i2 = 0; i2 < 2; ++i2) {
        #pragma unroll
        for (int jd = 0; jd < 4; ++jd) Racc[i2][jd] = mfma16(ea[i2], bv_[jd], Racc[i2][jd]);
        Zacc[i2] = mfma16(ea[i2], bones, Zacc[i2]);
      }
    }
  }
  #pragma unroll
  for (int i2 = 0; i2 < 2; ++i2) {
    int t0 = wave * 32 + i2 * 16 + quad * 4;
    #pragma unroll
    for (int jd = 0; jd < 4; ++jd) {
      int d = jd * 16 + l15;
      *(f32x4*)&RpT[(((size_t)qidx * 256 + bh) * 64 + d) * 128 + t0] = Racc[i2][jd];
    }
    if (l15 == 0) {
      #pragma unroll
      for (int r = 0; r < 4; ++r)
        Zp[((size_t)qidx * 256 + bh) * 128 + t0 + r] = Zacc[i2][r];
    }
  }
}

// ---------------- reduce partials: G = R/Z^2 -> Gt[bh][d][t] bf16 ---------------
__global__ void kt_reduce(const float* __restrict__ RpT, const float* __restrict__ Zp,
                          unsigned short* __restrict__ Gt) {
  size_t id = (size_t)blockIdx.x * 256 + threadIdx.x;
  int t = (int)(id & 127);
  size_t bh = id >> 13;
  float z = 0.f, r = 0.f;
  #pragma unroll
  for (int q = 0; q < 4; ++q) {
    z += Zp[(size_t)q * 32768 + bh * 128 + t];
    r += RpT[(size_t)q * 2097152 + id];
  }
  Gt[id] = f2bf(r / (z * z));
}

// ---------------- attention pass 2: out[s,d] = sum_t exp(S[t,s]) * G[t,d] -------
__global__ __launch_bounds__(256, 2) void kt_attn2(
    const unsigned short* __restrict__ Qb, const unsigned short* __restrict__ Kb,
    const unsigned short* __restrict__ Gt, unsigned short* __restrict__ Ao) {
  __shared__ __align__(16) unsigned short Ks[64 * 64];
  __shared__ __align__(16) unsigned short EsT[64 * 136];
  const int tid = threadIdx.x, lane = tid & 63, wave = tid >> 6;
  const int l15 = lane & 15, quad = lane >> 4;
  const int bid = blockIdx.x;
  const int lid = (bid & 7) * 128 + (bid >> 3);   // bijective chunked swizzle
  const int c = lid & 3, bh = lid >> 2;
  const int h = bh & 15, b = bh >> 4;
  s16x8 qf[8][2], gf[4][4];
  #pragma unroll
  for (int jt = 0; jt < 8; ++jt)
    #pragma unroll
    for (int kk = 0; kk < 2; ++kk)
      qf[jt][kk] = *(const s16x8*)&Qb[((size_t)bh * 128 + jt * 16 + l15) * 64 + kk * 32 + quad * 8];
  #pragma unroll
  for (int jd = 0; jd < 4; ++jd)
    #pragma unroll
    for (int kk = 0; kk < 4; ++kk)
      gf[jd][kk] = *(const s16x8*)&Gt[((size_t)bh * 64 + jd * 16 + l15) * 128 + kk * 32 + quad * 8];
  const size_t kbase = (size_t)bh * 4096 * 64;
  for (int it = 0; it < 16; ++it) {
    const int s0 = c * 1024 + it * 64;
    __syncthreads();
    #pragma unroll
    for (int i = 0; i < 2; ++i) {
      int srow = (wave * 2 + i) * 8 + (lane >> 3);
      glds16(Kb + kbase + (size_t)(s0 + srow) * 64 + (lane & 7) * 8, &Ks[(wave * 2 + i) * 512]);
    }
    __syncthreads();
    f32x4 Sacc[8] = {};
    #pragma unroll
    for (int kk = 0; kk < 2; ++kk) {
      s16x8 a = *(const s16x8*)&Ks[(wave * 16 + l15) * 64 + kk * 32 + quad * 8];
      #pragma unroll
      for (int jt = 0; jt < 8; ++jt) Sacc[jt] = mfma16(a, qf[jt][kk], Sacc[jt]);
    }
    #pragma unroll
    for (int jt = 0; jt < 8; ++jt)
      #pragma unroll
      for (int r = 0; r < 4; ++r)
        EsT[(wave * 16 + quad * 4 + r) * 136 + jt * 16 + l15] = f2bf(__expf(Sacc[jt][r]));
    f32x4 Oacc[4] = {};
    #pragma unroll
    for (int kk = 0; kk < 4; ++kk) {
      s16x8 ea = *(const s16x8*)&EsT[(wave * 16 + l15) * 136 + kk * 32 + quad * 8];
      #pragma unroll
      for (int jd = 0; jd < 4; ++jd) Oacc[jd] = mfma16(ea, gf[jd][kk], Oacc[jd]);
    }
    #pragma unroll
    for (int jd = 0; jd < 4; ++jd)
      #pragma unroll
      for (int r = 0; r < 4; ++r) {
        int s = s0 + wave * 16 + quad * 4 + r;
        int d = jd * 16 + l15;
        Ao[((size_t)b * 4096 + s) * 1024 + h * 64 + d] = f2bf(Oacc[jd][r]);
      }
  }
}

// --------------------------------- launch ---------------------------------------
extern "C" void kernel_launch(void* const* d_in, const int* in_sizes, int n_in,
                              void* d_out, int out_size, void* d_ws, size_t ws_size,
                              hipStream_t stream) {
  const float* hidden = (const float*)d_in[0];
  const float* text   = (const float*)d_in[1];
  const float* Wq = (const float*)d_in[2]; const float* bq = (const float*)d_in[3];
  const float* Wk = (const float*)d_in[4]; const float* bk = (const float*)d_in[5];
  const float* Wv = (const float*)d_in[6]; const float* bv = (const float*)d_in[7];
  const float* Wo = (const float*)d_in[8]; const float* bo = (const float*)d_in[9];
  char* ws = (char*)d_ws;
  unsigned short* WqT = (unsigned short*)(ws + (size_t)0);
  unsigned short* WkT = (unsigned short*)(ws + ((size_t)2 << 20));  // [WkT;WvT] contiguous
  unsigned short* WvT = (unsigned short*)(ws + ((size_t)4 << 20));  //   = merged N=2048 B
  unsigned short* WoT = (unsigned short*)(ws + ((size_t)6 << 20));
  unsigned short* Qb  = (unsigned short*)(ws + ((size_t)8 << 20));    // 4 MiB
  unsigned short* Kb  = (unsigned short*)(ws + ((size_t)12 << 20));   // 128 MiB
  unsigned short* Vt  = (unsigned short*)(ws + ((size_t)140 << 20));  // 128 MiB
  // Hb (bf16 hidden) overlays Ao: disjoint live ranges, stream-ordered.
  unsigned short* Hb  = (unsigned short*)(ws + ((size_t)268 << 20));  // 128 MiB
  unsigned short* Ao  = (unsigned short*)(ws + ((size_t)268 << 20));  // 128 MiB
  float*          RpT = (float*)(ws + ((size_t)396 << 20));           // 32 MiB
  float*          Zp  = (float*)(ws + ((size_t)428 << 20));           // 0.5 MiB
  unsigned short* Gt  = (unsigned short*)(ws + ((size_t)429 << 20));  // 4 MiB -> 433 MiB total

  dim3 blk(256);
  kt_transpose<<<dim3(16, 16), dim3(64, 4), 0, stream>>>(Wq, WqT);
  kt_transpose<<<dim3(16, 16), dim3(64, 4), 0, stream>>>(Wk, WkT);
  kt_transpose<<<dim3(16, 16), dim3(64, 4), 0, stream>>>(Wv, WvT);
  kt_transpose<<<dim3(16, 16), dim3(64, 4), 0, stream>>>(Wo, WoT);
  kt_cvt<<<dim3(2048), blk, 0, stream>>>(hidden, Hb);
  kt_gemm_q<<<dim3(8, 16), blk, 0, stream>>>(text, WqT, bq, Qb);
  kt_gemm256<0><<<dim3(2048), dim3(512), 0, stream>>>(Hb, WkT, bk, bv, Kb, Vt);
  kt_attn1<<<dim3(1024), blk, 0, stream>>>(Qb, Kb, Vt, RpT, Zp);
  kt_reduce<<<dim3(8192), blk, 0, stream>>>(RpT, Zp, Gt);
  kt_attn2<<<dim3(1024), blk, 0, stream>>>(Qb, Kb, Gt, Ao);
  kt_gemm256<2><<<dim3(1024), dim3(512), 0, stream>>>(Ao, WoT, bo, nullptr, d_out, nullptr);
}

// Round 4
// 1160.625 us; speedup vs baseline: 1.0303x; 1.0303x over previous
//
#include <hip/hip_runtime.h>
#include <stdint.h>

// Problem constants: B=16, Lt=128, Lv=4096, D=1024, H=16, HD=64
typedef short  s16x8 __attribute__((ext_vector_type(8)));   // 8 bf16 (4 VGPR) MFMA frag
typedef float  f32x4 __attribute__((ext_vector_type(4)));   // MFMA acc
typedef unsigned short u16x4 __attribute__((ext_vector_type(4)));

__device__ __forceinline__ unsigned short f2bf(float f) {   // RNE f32->bf16
  unsigned u = __builtin_bit_cast(unsigned, f);
  u = (u + 0x7fffu + ((u >> 16) & 1u)) >> 16;
  return (unsigned short)u;
}

__device__ __forceinline__ void glds16(const void* g, void* l) {
  // async global->LDS, 16B/lane; LDS dst = wave-uniform base + lane*16
  __builtin_amdgcn_global_load_lds((const __attribute__((address_space(1))) void*)g,
                                   (__attribute__((address_space(3))) void*)l, 16, 0, 0);
}

__device__ __forceinline__ f32x4 mfma16(s16x8 a, s16x8 b, f32x4 c) {
  return __builtin_amdgcn_mfma_f32_16x16x32_bf16(a, b, c, 0, 0, 0);
}

#define VM4 asm volatile("s_waitcnt vmcnt(4)" ::: "memory")
#define VM0 asm volatile("s_waitcnt vmcnt(0)" ::: "memory")

// ---------------- hidden fp32 -> bf16 one-pass convert (memory-bound) ----------
__global__ __launch_bounds__(256) void kt_cvt(const float* __restrict__ X,
                                              unsigned short* __restrict__ Y) {
  const size_t N8 = (size_t)16 * 4096 * 1024 / 8;
  for (size_t i = (size_t)blockIdx.x * 256 + threadIdx.x; i < N8;
       i += (size_t)gridDim.x * 256) {
    const float* g = X + i * 8;
    f32x4 a = *(const f32x4*)g;
    f32x4 b = *(const f32x4*)(g + 4);
    s16x8 o;
    o[0]=f2bf(a[0]); o[1]=f2bf(a[1]); o[2]=f2bf(a[2]); o[3]=f2bf(a[3]);
    o[4]=f2bf(b[0]); o[5]=f2bf(b[1]); o[6]=f2bf(b[2]); o[7]=f2bf(b[3]);
    *(s16x8*)(Y + i * 8) = o;
  }
}

// ---------------- weight transpose: W[k][n] f32 -> WT[n][k] bf16 -----------------
__global__ void kt_transpose(const float* __restrict__ W, unsigned short* __restrict__ WT) {
  __shared__ float tile[64][65];
  int n0 = blockIdx.x * 64, k0 = blockIdx.y * 64;
  int tx = threadIdx.x, ty = threadIdx.y;  // 64 x 4
  #pragma unroll
  for (int r = ty; r < 64; r += 4)
    tile[r][tx] = W[(size_t)(k0 + r) * 1024 + n0 + tx];
  __syncthreads();
  #pragma unroll
  for (int r = ty; r < 64; r += 4)
    WT[(size_t)(n0 + r) * 1024 + k0 + tx] = f2bf(tile[tx][r]);
}

// ---------------- small GEMM (Q projection): C = A(M,1024)@BT^T + bias ----------
// A fp32 (text), out bf16 Qb with torch-.view scramble + *0.125
__global__ __launch_bounds__(256, 2) void kt_gemm_q(
    const float* __restrict__ Ain, const unsigned short* __restrict__ BT,
    const float* __restrict__ bias, unsigned short* __restrict__ Cout) {
  __shared__ __align__(16) unsigned short As[128 * 32];
  __shared__ __align__(16) unsigned short Bs[128 * 32];
  const int tid = threadIdx.x, lane = tid & 63, wave = tid >> 6;
  const int l15 = lane & 15, quad = lane >> 4;
  const int wr = wave >> 1, wc = wave & 1;
  const int n0 = blockIdx.x * 128, m0 = blockIdx.y * 128;

  f32x4 acc[4][4] = {};
  for (int k0 = 0; k0 < 1024; k0 += 32) {
    __syncthreads();
    #pragma unroll
    for (int i = 0; i < 2; ++i) {
      int rowb = (wave * 2 + i) * 16 + (lane >> 2);
      glds16(BT + (size_t)(n0 + rowb) * 1024 + k0 + (lane & 3) * 8,
             &Bs[(wave * 2 + i) * 512]);
    }
    {
      const float* A = Ain;
      int row = tid >> 1, ks = (tid & 1) * 16;
      const float* g = &A[(size_t)(m0 + row) * 1024 + k0 + ks];
      f32x4 fa = *(const f32x4*)(g);
      f32x4 fb = *(const f32x4*)(g + 4);
      f32x4 fc = *(const f32x4*)(g + 8);
      f32x4 fd = *(const f32x4*)(g + 12);
      s16x8 lo, hi;
      lo[0]=f2bf(fa[0]); lo[1]=f2bf(fa[1]); lo[2]=f2bf(fa[2]); lo[3]=f2bf(fa[3]);
      lo[4]=f2bf(fb[0]); lo[5]=f2bf(fb[1]); lo[6]=f2bf(fb[2]); lo[7]=f2bf(fb[3]);
      hi[0]=f2bf(fc[0]); hi[1]=f2bf(fc[1]); hi[2]=f2bf(fc[2]); hi[3]=f2bf(fc[3]);
      hi[4]=f2bf(fd[0]); hi[5]=f2bf(fd[1]); hi[6]=f2bf(fd[2]); hi[7]=f2bf(fd[3]);
      *(s16x8*)&As[row * 32 + ks] = lo;
      *(s16x8*)&As[row * 32 + ks + 8] = hi;
    }
    __syncthreads();
    s16x8 a[4], b[4];
    #pragma unroll
    for (int i = 0; i < 4; ++i) a[i] = *(const s16x8*)&As[(wr * 64 + i * 16 + l15) * 32 + quad * 8];
    #pragma unroll
    for (int j = 0; j < 4; ++j) b[j] = *(const s16x8*)&Bs[(wc * 64 + j * 16 + l15) * 32 + quad * 8];
    #pragma unroll
    for (int i = 0; i < 4; ++i)
      #pragma unroll
      for (int j = 0; j < 4; ++j) acc[i][j] = mfma16(a[i], b[j], acc[i][j]);
  }
  #pragma unroll
  for (int j = 0; j < 4; ++j) {
    int col = n0 + wc * 64 + j * 16 + l15;
    float bv = bias[col];
    #pragma unroll
    for (int i = 0; i < 4; ++i)
      #pragma unroll
      for (int r = 0; r < 4; ++r) {
        int row = m0 + wr * 64 + i * 16 + quad * 4 + r;
        float v = (acc[i][j][r] + bv) * 0.125f;
        size_t idx = ((size_t)((row >> 7) * 16 + (col >> 6)) * 128 + (row & 127)) * 64 + (col & 63);
        Cout[idx] = f2bf(v);
      }
  }
}

// ---------------- 256x256 8-phase bf16 GEMM (T1+T2+T3+T4+T5) --------------------
// MODE 0: fused K+V projection, BT=[WkT;WvT], N=2048. MODE 2: O-proj, fp32 out.
// (unchanged from round 3 -- see header comments there)
template <int MODE>
__global__ __launch_bounds__(512, 2) void kt_gemm256(
    const unsigned short* __restrict__ A, const unsigned short* __restrict__ BT,
    const float* __restrict__ bias0, const float* __restrict__ bias1,
    void* __restrict__ out0, void* __restrict__ out1) {
  constexpr int NN = (MODE == 0) ? 8 : 4;          // n-blocks
  constexpr int CHUNK = (MODE == 0) ? 256 : 128;   // nwg/8
  __shared__ __align__(16) unsigned short lds[65536];  // 128 KiB
  const int tid = threadIdx.x, lane = tid & 63, wave = tid >> 6;
  const int l15 = lane & 15, quad = lane >> 4;
  const int wr = wave >> 2, wc = wave & 3;        // 2M x 4N waves
  const int r0 = lane >> 3, sck = (lane & 7) ^ r0; // stage source pre-swizzle
  const int bid = blockIdx.x;
  const int logical = (bid & 7) * CHUNK + (bid >> 3);   // bijective chunked swizzle
  const int nblk = logical & (NN - 1), mblk = logical / NN;
  const int n0 = nblk * 256, m0 = mblk * 256;
  const unsigned short* Asrc = A + (size_t)m0 * 1024;
  const unsigned short* Bsrc = BT + (size_t)n0 * 1024;

  f32x4 acc[8][4] = {};
  s16x8 bf_[4][2];

  auto stageA = [&](int t, int h, int buf) {
    #pragma unroll
    for (int is = 0; is < 2; ++is) {
      int c = wave * 2 + is;
      glds16(Asrc + (size_t)(h * 128 + c * 8 + r0) * 1024 + t * 64 + sck * 8,
             &lds[buf * 32768 + h * 8192 + c * 512]);
    }
  };
  auto stageB = [&](int t, int h, int buf) {
    #pragma unroll
    for (int is = 0; is < 2; ++is) {
      int c = wave * 2 + is;
      glds16(Bsrc + (size_t)(h * 128 + c * 8 + r0) * 1024 + t * 64 + sck * 8,
             &lds[buf * 32768 + 16384 + h * 8192 + c * 512]);
    }
  };

  stageA(0, 0, 0); stageA(0, 1, 0); stageB(0, 0, 0); stageB(0, 1, 0);
  stageB(1, 0, 1); stageB(1, 1, 1);
  VM4;
  __builtin_amdgcn_s_barrier();

  #pragma unroll 1
  for (int it = 0; it < 8; ++it) {
    const bool last = (it == 7);
    const int te = 2 * it;
    #pragma unroll
    for (int half = 0; half < 2; ++half) {
      const int buf = half;
      #pragma unroll
      for (int p = 0; p < 4; ++p) {
        if (p == 0) {
          #pragma unroll
          for (int j = 0; j < 4; ++j)
            #pragma unroll
            for (int kk = 0; kk < 2; ++kk) {
              int r = (wc & 1) * 64 + j * 16 + l15;
              bf_[j][kk] = *(const s16x8*)&lds[buf * 32768 + 16384 + (wc >> 1) * 8192
                                               + r * 64 + (((kk * 4 + quad) ^ (r & 7)) << 3)];
            }
        }
        s16x8 af[2][2];
        #pragma unroll
        for (int ii = 0; ii < 2; ++ii)
          #pragma unroll
          for (int kk = 0; kk < 2; ++kk) {
            int r = (p * 2 + ii) * 16 + l15;
            af[ii][kk] = *(const s16x8*)&lds[buf * 32768 + wr * 8192
                                             + r * 64 + (((kk * 4 + quad) ^ (r & 7)) << 3)];
          }
        if (half == 0) {
          if (p == 0) { stageA(te + 1, 0, 1); stageA(te + 1, 1, 1); }
          else if (p == 1) { if (!last) stageB(te + 2, 0, 0); }
          else if (p == 2) { if (!last) stageB(te + 2, 1, 0); }
        } else {
          if (p == 0) { if (!last) stageA(te + 2, 0, 0); }
          else if (p == 1) { if (!last) { stageA(te + 2, 1, 0); stageB(te + 3, 0, 1); } }
          else if (p == 2) { if (!last) stageB(te + 3, 1, 1); }
        }
        __builtin_amdgcn_s_barrier();
        __builtin_amdgcn_s_setprio(1);
        #pragma unroll
        for (int ii = 0; ii < 2; ++ii)
          #pragma unroll
          for (int j = 0; j < 4; ++j)
            #pragma unroll
            for (int kk = 0; kk < 2; ++kk)
              acc[p * 2 + ii][j] = mfma16(af[ii][kk], bf_[j][kk], acc[p * 2 + ii][j]);
        __builtin_amdgcn_s_setprio(0);
        if (p == 3) {
          if (half == 0) { if (last) { VM0; } else { VM4; } }
          else           { if (!last) { VM4; } }
        }
        __builtin_amdgcn_s_barrier();
      }
    }
  }

  const int bb = m0 >> 12;
  const bool isV = (MODE == 0) && (n0 >= 1024);
  const float* bias = isV ? bias1 : bias0;
  #pragma unroll
  for (int j = 0; j < 4; ++j) {
    const int colg = n0 + wc * 64 + j * 16 + l15;
    const int c1 = colg & 1023;
    const float bv = bias[c1];
    const int hcol = c1 >> 6, dcol = c1 & 63;
    #pragma unroll
    for (int i = 0; i < 8; ++i) {
      const int row0 = m0 + wr * 128 + i * 16 + quad * 4;
      const int s = row0 & 4095;
      if constexpr (MODE == 0) {
        if (isV) {
          size_t base = (((size_t)bb * 16 + hcol) * 64 + dcol) * 4096 + s;
          u16x4 w;
          #pragma unroll
          for (int r = 0; r < 4; ++r) w[r] = f2bf(acc[i][j][r] + bv);
          *(u16x4*)&((unsigned short*)out1)[base] = w;
        } else {
          unsigned short* Ko = (unsigned short*)out0;
          size_t base = (((size_t)bb * 16 + hcol) * 4096 + s) * 64 + dcol;
          #pragma unroll
          for (int r = 0; r < 4; ++r) Ko[base + (size_t)r * 64] = f2bf(acc[i][j][r] + bv);
        }
      } else {
        float* O = (float*)out0;
        size_t base = (size_t)row0 * 1024 + colg;
        #pragma unroll
        for (int r = 0; r < 4; ++r) O[base + (size_t)r * 1024] = acc[i][j][r] + bv;
      }
    }
  }
}

// ---------------- attention pass 1: R[t,d]=sum_s exp(S)*v, Z[t]=sum_s exp(S) ----
// 8 waves x 16 t-rows. K/V double-buffered + chunk-XOR swizzled (16-way -> 2-way
// bank conflicts on frag reads); E held in conflict-free per-wave [16][40] strips,
// consumed per-32-col quarter. Issue-early stage, drain-late, 1 barrier/chunk.
__global__ __launch_bounds__(512, 4) void kt_attn1(
    const unsigned short* __restrict__ Qb, const unsigned short* __restrict__ Kb,
    const unsigned short* __restrict__ Vt, float* __restrict__ RpT,
    float* __restrict__ Zp) {
  __shared__ __align__(16) unsigned short Ks[2][128 * 64];   // [s][d] swizzled, 2x16 KiB
  __shared__ __align__(16) unsigned short Vts[2][64 * 128];  // [d][s] swizzled, 2x16 KiB
  __shared__ __align__(16) unsigned short Es[8][16 * 40];    // per-wave E strip, 10 KiB
  const int tid = threadIdx.x, lane = tid & 63, wave = tid >> 6;
  const int l15 = lane & 15, quad = lane >> 4;
  const int bid = blockIdx.x;
  const int lid = (bid & 7) * 128 + (bid >> 3);   // bijective chunked XCD swizzle
  const int qidx = lid & 3, bh = lid >> 2;
  const size_t kbase = (size_t)bh * 4096 * 64;
  const size_t vbase = (size_t)bh * 64 * 4096;
  s16x8 qa[2];  // Q A-frags: wave's 16 t-rows
  #pragma unroll
  for (int kk = 0; kk < 2; ++kk)
    qa[kk] = *(const s16x8*)&Qb[((size_t)bh * 128 + wave * 16 + l15) * 64 + kk * 32 + quad * 8];
  s16x8 bones;
  { unsigned short o = (l15 == 0) ? (unsigned short)0x3F80 : (unsigned short)0;
    #pragma unroll
    for (int c2 = 0; c2 < 8; ++c2) bones[c2] = (short)o; }
  f32x4 Racc[4] = {};
  f32x4 Zacc = {};

  auto stage = [&](int ch, int buf) {
    const int s0 = qidx * 1024 + ch * 128;
    #pragma unroll
    for (int i = 0; i < 2; ++i) {   // K chunk 128x64: wave stages 16 rows
      int srow = wave * 16 + i * 8 + (lane >> 3);
      int ck = (lane & 7) ^ (srow & 7);          // pre-swizzled global source
      glds16(Kb + kbase + (size_t)(s0 + srow) * 64 + ck * 8,
             &Ks[buf][(wave * 16 + i * 8) * 64]);
    }
    #pragma unroll
    for (int i = 0; i < 2; ++i) {   // V^T chunk 64x128: wave stages 8 rows
      int drow = wave * 8 + i * 4 + (lane >> 4);
      int ck = (lane & 15) ^ (drow & 15);
      glds16(Vt + vbase + (size_t)drow * 4096 + s0 + ck * 8,
             &Vts[buf][(wave * 8 + i * 4) * 128]);
    }
  };

  stage(0, 0);
  VM0;
  __syncthreads();

  #pragma unroll 1
  for (int ch = 0; ch < 8; ++ch) {
    const int buf = ch & 1;
    if (ch < 7) stage(ch + 1, buf ^ 1);   // issue early, drain after compute
    // S = Q K^T (wave's 16 t-rows x 128 s-cols)
    f32x4 Sacc[8] = {};
    #pragma unroll
    for (int kk = 0; kk < 2; ++kk)
      #pragma unroll
      for (int jh = 0; jh < 2; ++jh) {
        s16x8 bk[4];
        #pragma unroll
        for (int j = 0; j < 4; ++j) {
          int r = (jh * 4 + j) * 16 + l15;
          bk[j] = *(const s16x8*)&Ks[buf][r * 64 + (((kk * 4 + quad) ^ (r & 7)) << 3)];
        }
        #pragma unroll
        for (int j = 0; j < 4; ++j)
          Sacc[jh * 4 + j] = mfma16(qa[kk], bk[j], Sacc[jh * 4 + j]);
      }
    // per-32-col quarter: E write (wave-private strip) -> A-frag read -> PV
    #pragma unroll
    for (int kk2 = 0; kk2 < 4; ++kk2) {
      #pragma unroll
      for (int jl = 0; jl < 2; ++jl) {
        int j = kk2 * 2 + jl;
        #pragma unroll
        for (int r = 0; r < 4; ++r)
          Es[wave][(quad * 4 + r) * 40 + jl * 16 + l15] = f2bf(__expf(Sacc[j][r]));
      }
      s16x8 ea = *(const s16x8*)&Es[wave][l15 * 40 + quad * 8];
      s16x8 bv[4];
      #pragma unroll
      for (int jd = 0; jd < 4; ++jd) {
        int r = jd * 16 + l15;
        bv[jd] = *(const s16x8*)&Vts[buf][r * 128 + (((kk2 * 4 + quad) ^ (r & 15)) << 3)];
      }
      #pragma unroll
      for (int jd = 0; jd < 4; ++jd) Racc[jd] = mfma16(ea, bv[jd], Racc[jd]);
      Zacc = mfma16(ea, bones, Zacc);
    }
    if (ch < 7) VM0;
    __syncthreads();
  }
  // RpT[q][bh][d][t] (float4 over t), Zp[q][bh][t]
  int t0 = wave * 16 + quad * 4;
  #pragma unroll
  for (int jd = 0; jd < 4; ++jd) {
    int d = jd * 16 + l15;
    *(f32x4*)&RpT[(((size_t)qidx * 256 + bh) * 64 + d) * 128 + t0] = Racc[jd];
  }
  if (l15 == 0) {
    #pragma unroll
    for (int r = 0; r < 4; ++r)
      Zp[((size_t)qidx * 256 + bh) * 128 + t0 + r] = Zacc[r];
  }
}

// ---------------- reduce partials: G = R/Z^2 -> Gt[bh][d][t] bf16 ---------------
__global__ void kt_reduce(const float* __restrict__ RpT, const float* __restrict__ Zp,
                          unsigned short* __restrict__ Gt) {
  size_t id = (size_t)blockIdx.x * 256 + threadIdx.x;
  int t = (int)(id & 127);
  size_t bh = id >> 13;
  float z = 0.f, r = 0.f;
  #pragma unroll
  for (int q = 0; q < 4; ++q) {
    z += Zp[(size_t)q * 32768 + bh * 128 + t];
    r += RpT[(size_t)q * 2097152 + id];
  }
  Gt[id] = f2bf(r / (z * z));
}

// ---------------- attention pass 2: out[s,d] = sum_t exp(S[t,s]) * G[t,d] -------
// K double-buffered + chunk-XOR swizzled; issue-early/drain-late, 1 barrier/iter.
__global__ __launch_bounds__(256, 2) void kt_attn2(
    const unsigned short* __restrict__ Qb, const unsigned short* __restrict__ Kb,
    const unsigned short* __restrict__ Gt, unsigned short* __restrict__ Ao) {
  __shared__ __align__(16) unsigned short Ks[2][64 * 64];  // [s][d] swizzled, 2x8 KiB
  __shared__ __align__(16) unsigned short EsT[64 * 136];   // [s][t], stride 136
  const int tid = threadIdx.x, lane = tid & 63, wave = tid >> 6;
  const int l15 = lane & 15, quad = lane >> 4;
  const int bid = blockIdx.x;
  const int lid = (bid & 7) * 128 + (bid >> 3);   // bijective chunked XCD swizzle
  const int c = lid & 3, bh = lid >> 2;
  const int h = bh & 15, b = bh >> 4;
  s16x8 qf[8][2], gf[4][4];
  #pragma unroll
  for (int jt = 0; jt < 8; ++jt)
    #pragma unroll
    for (int kk = 0; kk < 2; ++kk)
      qf[jt][kk] = *(const s16x8*)&Qb[((size_t)bh * 128 + jt * 16 + l15) * 64 + kk * 32 + quad * 8];
  #pragma unroll
  for (int jd = 0; jd < 4; ++jd)
    #pragma unroll
    for (int kk = 0; kk < 4; ++kk)
      gf[jd][kk] = *(const s16x8*)&Gt[((size_t)bh * 64 + jd * 16 + l15) * 128 + kk * 32 + quad * 8];
  const size_t kbase = (size_t)bh * 4096 * 64;

  auto stage = [&](int it, int buf) {
    const int s0 = c * 1024 + it * 64;
    #pragma unroll
    for (int i = 0; i < 2; ++i) {
      int srow = wave * 16 + i * 8 + (lane >> 3);
      int ck = (lane & 7) ^ (srow & 7);
      glds16(Kb + kbase + (size_t)(s0 + srow) * 64 + ck * 8,
             &Ks[buf][(wave * 16 + i * 8) * 64]);
    }
  };

  stage(0, 0);
  VM0;
  __syncthreads();

  #pragma unroll 1
  for (int it = 0; it < 16; ++it) {
    const int buf = it & 1;
    if (it < 15) stage(it + 1, buf ^ 1);
    const int s0 = c * 1024 + it * 64;
    f32x4 Sacc[8] = {};
    #pragma unroll
    for (int kk = 0; kk < 2; ++kk) {
      int r = wave * 16 + l15;
      s16x8 a = *(const s16x8*)&Ks[buf][r * 64 + (((kk * 4 + quad) ^ (r & 7)) << 3)];
      #pragma unroll
      for (int jt = 0; jt < 8; ++jt) Sacc[jt] = mfma16(a, qf[jt][kk], Sacc[jt]);
    }
    #pragma unroll
    for (int jt = 0; jt < 8; ++jt)
      #pragma unroll
      for (int r = 0; r < 4; ++r)
        EsT[(wave * 16 + quad * 4 + r) * 136 + jt * 16 + l15] = f2bf(__expf(Sacc[jt][r]));
    f32x4 Oacc[4] = {};
    #pragma unroll
    for (int kk = 0; kk < 4; ++kk) {
      s16x8 ea = *(const s16x8*)&EsT[(wave * 16 + l15) * 136 + kk * 32 + quad * 8];
      #pragma unroll
      for (int jd = 0; jd < 4; ++jd) Oacc[jd] = mfma16(ea, gf[jd][kk], Oacc[jd]);
    }
    #pragma unroll
    for (int jd = 0; jd < 4; ++jd)
      #pragma unroll
      for (int r = 0; r < 4; ++r) {
        int s = s0 + wave * 16 + quad * 4 + r;
        int d = jd * 16 + l15;
        Ao[((size_t)b * 4096 + s) * 1024 + h * 64 + d] = f2bf(Oacc[jd][r]);
      }
    if (it < 15) VM0;
    __syncthreads();
  }
}

// --------------------------------- launch ---------------------------------------
extern "C" void kernel_launch(void* const* d_in, const int* in_sizes, int n_in,
                              void* d_out, int out_size, void* d_ws, size_t ws_size,
                              hipStream_t stream) {
  const float* hidden = (const float*)d_in[0];
  const float* text   = (const float*)d_in[1];
  const float* Wq = (const float*)d_in[2]; const float* bq = (const float*)d_in[3];
  const float* Wk = (const float*)d_in[4]; const float* bk = (const float*)d_in[5];
  const float* Wv = (const float*)d_in[6]; const float* bv = (const float*)d_in[7];
  const float* Wo = (const float*)d_in[8]; const float* bo = (const float*)d_in[9];
  char* ws = (char*)d_ws;
  unsigned short* WqT = (unsigned short*)(ws + (size_t)0);
  unsigned short* WkT = (unsigned short*)(ws + ((size_t)2 << 20));  // [WkT;WvT] contiguous
  unsigned short* WvT = (unsigned short*)(ws + ((size_t)4 << 20));  //   = merged N=2048 B
  unsigned short* WoT = (unsigned short*)(ws + ((size_t)6 << 20));
  unsigned short* Qb  = (unsigned short*)(ws + ((size_t)8 << 20));    // 4 MiB
  unsigned short* Kb  = (unsigned short*)(ws + ((size_t)12 << 20));   // 128 MiB
  unsigned short* Vt  = (unsigned short*)(ws + ((size_t)140 << 20));  // 128 MiB
  // Hb (bf16 hidden) overlays Ao: disjoint live ranges, stream-ordered.
  unsigned short* Hb  = (unsigned short*)(ws + ((size_t)268 << 20));  // 128 MiB
  unsigned short* Ao  = (unsigned short*)(ws + ((size_t)268 << 20));  // 128 MiB
  float*          RpT = (float*)(ws + ((size_t)396 << 20));           // 32 MiB
  float*          Zp  = (float*)(ws + ((size_t)428 << 20));           // 0.5 MiB
  unsigned short* Gt  = (unsigned short*)(ws + ((size_t)429 << 20));  // 4 MiB -> 433 MiB total

  dim3 blk(256);
  kt_transpose<<<dim3(16, 16), dim3(64, 4), 0, stream>>>(Wq, WqT);
  kt_transpose<<<dim3(16, 16), dim3(64, 4), 0, stream>>>(Wk, WkT);
  kt_transpose<<<dim3(16, 16), dim3(64, 4), 0, stream>>>(Wv, WvT);
  kt_transpose<<<dim3(16, 16), dim3(64, 4), 0, stream>>>(Wo, WoT);
  kt_cvt<<<dim3(2048), blk, 0, stream>>>(hidden, Hb);
  kt_gemm_q<<<dim3(8, 16), blk, 0, stream>>>(text, WqT, bq, Qb);
  kt_gemm256<0><<<dim3(2048), dim3(512), 0, stream>>>(Hb, WkT, bk, bv, Kb, Vt);
  kt_attn1<<<dim3(1024), dim3(512), 0, stream>>>(Qb, Kb, Vt, RpT, Zp);
  kt_reduce<<<dim3(8192), blk, 0, stream>>>(RpT, Zp, Gt);
  kt_attn2<<<dim3(1024), blk, 0, stream>>>(Qb, Kb, Gt, Ao);
  kt_gemm256<2><<<dim3(1024), dim3(512), 0, stream>>>(Ao, WoT, bo, nullptr, d_out, nullptr);
}